// Round 10
// baseline (613.284 us; speedup 1.0000x reference)
//
#include <hip/hip_runtime.h>
#include <math.h>

constexpr int B  = 128;
constexpr int L  = 512;
constexpr int D2 = 512;    // 2H
constexpr int D4 = 1024;   // 4H
constexpr int G3 = 3072;   // 3*4H
constexpr int R3 = 384;    // 3*B (branch-major rows: r = k*B + b)
constexpr int NC = 4096;   // cat N: [0,512) stt(norm only) | [512,3584) gh | [3584,4096) shat
constexpr float LAMDA = 3.0f;
constexpr float EPSF  = 1e-8f;

typedef __attribute__((ext_vector_type(8))) short bf16x8;
typedef __attribute__((ext_vector_type(8))) short short8;
typedef __attribute__((ext_vector_type(4))) float f32x4;

__device__ __forceinline__ ushort f2bf(float v) {
  uint u = __builtin_bit_cast(uint, v);
  u = (u + 0x7fffu + ((u >> 16) & 1u)) >> 16;   // RNE
  return (ushort)u;
}
__device__ __forceinline__ float bf2f(ushort h) {
  return __builtin_bit_cast(float, (uint)h << 16);
}
__device__ __forceinline__ float bflo(uint w) { return __builtin_bit_cast(float, w << 16); }
__device__ __forceinline__ float bfhi(uint w) { return __builtin_bit_cast(float, w & 0xffff0000u); }
__device__ __forceinline__ void split2(float v, ushort& h, ushort& l) {
  h = f2bf(v);
  l = f2bf(v - bf2f(h));
}
// async global->LDS, 16B per lane; LDS dest = wave-uniform base + lane*16
__device__ __forceinline__ void gload_lds16(const void* g, void* l) {
  __builtin_amdgcn_global_load_lds(
      (const __attribute__((address_space(1))) unsigned int*)g,
      (__attribute__((address_space(3))) unsigned int*)l, 16, 0, 0);
}

// ---------------- init ----------------
__global__ void k_init(const float* __restrict__ s1, const float* __restrict__ s2,
                       const float* __restrict__ s3, float* __restrict__ st3,
                       ushort* __restrict__ sth, ushort* __restrict__ stl,
                       float* __restrict__ snacc, float* __restrict__ cacc,
                       float* __restrict__ o3) {
  int idx = blockIdx.x * blockDim.x + threadIdx.x;
  if (idx < R3) { snacc[idx] = 0.f; cacc[idx] = 0.f; o3[idx] = 0.f; }
  int total = R3 * D4;
  for (; idx < total; idx += gridDim.x * blockDim.x) {
    int r = idx / D4, i = idx - r * D4;
    int k = r / B, b = r - k * B;
    const float* s = (k == 0) ? s1 : (k == 1) ? s2 : s3;
    float v = s[b * D4 + i];
    st3[idx] = v;
    if (sth) { ushort h, l; split2(v, h, l); sth[idx] = h; stl[idx] = l; }
  }
}

// ---------------- conversions ----------------
__global__ void k_conv_m(const float* __restrict__ m, ushort* __restrict__ mbf) {
  int idx = blockIdx.x * blockDim.x + threadIdx.x;
  const int total8 = (B * L * D2) / 8;
  for (; idx < total8; idx += gridDim.x * blockDim.x) {
    const float4* p = reinterpret_cast<const float4*>(m) + (size_t)idx * 2;
    float4 a = p[0], c = p[1];
    ushort o[8] = {f2bf(a.x), f2bf(a.y), f2bf(a.z), f2bf(a.w),
                   f2bf(c.x), f2bf(c.y), f2bf(c.z), f2bf(c.w)};
    *reinterpret_cast<uint4*>(mbf + (size_t)idx * 8) = *reinterpret_cast<const uint4*>(o);
  }
}

__global__ void k_w2t(const float* __restrict__ w2, ushort* __restrict__ w2t) {
  __shared__ ushort t[64][65];
  int bk = (blockIdx.x & 7) * 64, bn = (blockIdx.x >> 3) * 64;
  int tid = threadIdx.x;
#pragma unroll
  for (int i = 0; i < 16; ++i) {
    int e = tid + i * 256; int r = e >> 6, c = e & 63;
    t[r][c] = f2bf(w2[(bk + r) * 512 + bn + c]);
  }
  __syncthreads();
#pragma unroll
  for (int i = 0; i < 16; ++i) {
    int e = tid + i * 256; int r = e >> 6, c = e & 63;
    w2t[(bn + r) * 512 + bk + c] = t[c][r];
  }
}

__global__ void k_split_direct(const float* __restrict__ in, ushort* __restrict__ oh,
                               ushort* __restrict__ ol, int n4) {
  int idx = blockIdx.x * blockDim.x + threadIdx.x;
  for (; idx < n4; idx += gridDim.x * blockDim.x) {
    float4 v = reinterpret_cast<const float4*>(in)[idx];
    ushort4 h, l;
    split2(v.x, h.x, l.x); split2(v.y, h.y, l.y);
    split2(v.z, h.z, l.z); split2(v.w, h.w, l.w);
    reinterpret_cast<ushort4*>(oh)[idx] = h;
    reinterpret_cast<ushort4*>(ol)[idx] = l;
  }
}

__global__ void k_split_trans(const float* __restrict__ in, int K, int N,
                              ushort* __restrict__ oh, ushort* __restrict__ ol) {
  __shared__ float t[64][65];
  int bk = blockIdx.x * 64, bn = blockIdx.y * 64;
  int tid = threadIdx.x;
#pragma unroll
  for (int i = 0; i < 16; ++i) {
    int e = tid + i * 256; int r = e >> 6, c = e & 63;
    t[r][c] = in[(size_t)(bk + r) * N + bn + c];
  }
  __syncthreads();
#pragma unroll
  for (int i = 0; i < 16; ++i) {
    int e = tid + i * 256; int r = e >> 6, c = e & 63;
    ushort h, l;
    split2(t[c][r], h, l);
    oh[(size_t)(bn + r) * K + bk + c] = h;
    ol[(size_t)(bn + r) * K + bk + c] = l;
  }
}

__global__ void k_bcat2(const float* __restrict__ w3b, const float* __restrict__ gbh,
                        const float* __restrict__ w2w, float* __restrict__ bcat) {
  int idx = blockIdx.x * 256 + threadIdx.x;
  if (idx < D2) bcat[idx] = w3b[idx];
  else if (idx < D2 + G3) bcat[idx] = gbh[idx - D2];
  else if (idx < NC) {
    int e = idx - (D2 + G3);
    float s = 0.f;
    for (int d = 0; d < D2; ++d) s = fmaf(w3b[d], w2w[(size_t)e * D2 + d], s);
    bcat[idx] = s;
  }
}

// ---------------- one-time: WfT[e][q] = dot(w2 row e, w3 row q) ----------------
__global__ __launch_bounds__(64) void k_gemm_wf(
    const ushort* __restrict__ Ahp, const ushort* __restrict__ Alp,
    const ushort* __restrict__ Bhp, const ushort* __restrict__ Blp,
    ushort* __restrict__ Ch, ushort* __restrict__ Cl) {
  const int ln = threadIdx.x;
  const int lrow = ln & 15, lk = ln >> 4;
  const int rowb = blockIdx.y * 64;
  const int colb = blockIdx.x * 64;
  size_t aoff[4], boff[4];
#pragma unroll
  for (int f = 0; f < 4; ++f) {
    aoff[f] = (size_t)(rowb + f * 16 + lrow) * D2 + lk * 8;
    boff[f] = (size_t)(colb + f * 16 + lrow) * D2 + lk * 8;
  }
  f32x4 acc[4][4] = {};
  for (int kc = 0; kc < D2; kc += 32) {
    bf16x8 ah[4], al[4], bh[4], bl[4];
#pragma unroll
    for (int f = 0; f < 4; ++f) {
      ah[f] = *reinterpret_cast<const bf16x8*>(Ahp + aoff[f] + kc);
      al[f] = *reinterpret_cast<const bf16x8*>(Alp + aoff[f] + kc);
      bh[f] = *reinterpret_cast<const bf16x8*>(Bhp + boff[f] + kc);
      bl[f] = *reinterpret_cast<const bf16x8*>(Blp + boff[f] + kc);
    }
#pragma unroll
    for (int rf = 0; rf < 4; ++rf)
#pragma unroll
      for (int cf = 0; cf < 4; ++cf) {
        acc[rf][cf] = __builtin_amdgcn_mfma_f32_16x16x32_bf16(ah[rf], bh[cf], acc[rf][cf], 0, 0, 0);
        acc[rf][cf] = __builtin_amdgcn_mfma_f32_16x16x32_bf16(al[rf], bh[cf], acc[rf][cf], 0, 0, 0);
        acc[rf][cf] = __builtin_amdgcn_mfma_f32_16x16x32_bf16(ah[rf], bl[cf], acc[rf][cf], 0, 0, 0);
      }
  }
#pragma unroll
  for (int rf = 0; rf < 4; ++rf)
#pragma unroll
    for (int cf = 0; cf < 4; ++cf) {
      int col = colb + cf * 16 + lrow;
#pragma unroll
      for (int j = 0; j < 4; ++j) {
        int row = rowb + rf * 16 + lk * 4 + j;
        ushort h, l;
        split2(acc[rf][cf][j], h, l);
        Ch[(size_t)row * D4 + col] = h;
        Cl[(size_t)row * D4 + col] = l;
      }
    }
}

// ---------------- m_norm^4: LDS-staged MFMA (validated R7) ----------------
__global__ __launch_bounds__(256, 2) void k_mnorm4(const ushort* __restrict__ mbf,
                                                   const ushort* __restrict__ w2t,
                                                   const float* __restrict__ b2,
                                                   float* __restrict__ norm2) {
  __shared__ ushort As[2][64 * 32];
  __shared__ ushort Bs[2][512 * 32];
  const int tid = threadIdx.x;
  const int wv = tid >> 6, ln = tid & 63;
  const int lrow = ln & 15, lk = ln >> 4;
  const size_t rowb = (size_t)blockIdx.x * 64;

  auto stage = [&](int buf, int kc) {
    {
      int li = wv * 64 + ln;
      int row = li >> 2, slot = li & 3;
      const ushort* src = mbf + (rowb + row) * 512 + kc + ((slot ^ (row & 3)) << 3);
      gload_lds16(src, &As[buf][(size_t)wv * 64 * 8]);
    }
#pragma unroll
    for (int i = 0; i < 8; ++i) {
      int c = wv * 8 + i;
      int li = c * 64 + ln;
      int col = li >> 2, slot = li & 3;
      const ushort* src = w2t + (size_t)col * 512 + kc + ((slot ^ (col & 3)) << 3);
      gload_lds16(src, &Bs[buf][(size_t)c * 64 * 8]);
    }
  };

  f32x4 acc[4][8] = {};
  stage(0, 0);
  __syncthreads();
  for (int t = 0; t < 16; ++t) {
    int cur = t & 1;
    if (t + 1 < 16) stage(cur ^ 1, (t + 1) * 32);
    bf16x8 af[4], bfr[8];
#pragma unroll
    for (int rf = 0; rf < 4; ++rf) {
      int row = rf * 16 + lrow;
      af[rf] = *reinterpret_cast<const bf16x8*>(&As[cur][row * 32 + ((lk ^ (row & 3)) << 3)]);
    }
#pragma unroll
    for (int cf = 0; cf < 8; ++cf) {
      int col = wv * 128 + cf * 16 + lrow;
      bfr[cf] = *reinterpret_cast<const bf16x8*>(&Bs[cur][col * 32 + ((lk ^ (col & 3)) << 3)]);
    }
#pragma unroll
    for (int rf = 0; rf < 4; ++rf)
#pragma unroll
      for (int cf = 0; cf < 8; ++cf)
        acc[rf][cf] = __builtin_amdgcn_mfma_f32_16x16x32_bf16(af[rf], bfr[cf], acc[rf][cf], 0, 0, 0);
    __syncthreads();
  }

  float nrm[4][4] = {};
#pragma unroll
  for (int cf = 0; cf < 8; ++cf) {
    float bb = b2[wv * 128 + cf * 16 + lrow];
#pragma unroll
    for (int rf = 0; rf < 4; ++rf)
#pragma unroll
      for (int j = 0; j < 4; ++j) {
        float v = acc[rf][cf][j] + bb;
        nrm[rf][j] = fmaf(v, v, nrm[rf][j]);
      }
  }
  __shared__ float red[4][64];
#pragma unroll
  for (int rf = 0; rf < 4; ++rf)
#pragma unroll
    for (int j = 0; j < 4; ++j) {
      float v = nrm[rf][j];
      v += __shfl_xor(v, 1); v += __shfl_xor(v, 2);
      v += __shfl_xor(v, 4); v += __shfl_xor(v, 8);
      if (lrow == 0) red[wv][rf * 16 + lk * 4 + j] = v;
    }
  __syncthreads();
  if (tid < 64)
    norm2[rowb + tid] = red[0][tid] + red[1][tid] + red[2][tid] + red[3][tid];
}

// ---------------- k_gemm6: 64x128 tile, 4 waves split-N (traffic-optimized) ----------------
// Traffic = A*(N/128) + B*(M/64) ~ half of the 32x64 version. No LDS, no K-split;
// bandwidth-bound, 16 waves/CU hide the serialized loads.
// EPI 0: outf = A@B + bias | EPI 1: cat (norm atomics | gh | shat) | EPI 2: relu + w5 atomics
template <int EPI>
__global__ __launch_bounds__(256) void k_gemm6(
    const ushort* __restrict__ Ahp, const ushort* __restrict__ Alp,
    const ushort* __restrict__ Bhp, const ushort* __restrict__ Blp,
    int Kd, const float* __restrict__ bias,
    float* __restrict__ outf, int ldc,
    float* __restrict__ gh, float* __restrict__ shat,
    float* __restrict__ snacc, float* __restrict__ cacc,
    const float* __restrict__ b2,
    const float* __restrict__ w5w, float* __restrict__ o3) {
  const int tid = threadIdx.x;
  const int wv = tid >> 6, ln = tid & 63;
  const int lrow = ln & 15, lk = ln >> 4;
  const int rowb = blockIdx.y * 64;
  const int colb = blockIdx.x * 128 + wv * 32;
  const ushort* ah0 = Ahp + (size_t)(rowb + lrow) * Kd + lk * 8;
  const ushort* al0 = Alp + (size_t)(rowb + lrow) * Kd + lk * 8;
  const ushort* bh0 = Bhp + (size_t)(colb + lrow) * Kd + lk * 8;
  const ushort* bl0 = Blp + (size_t)(colb + lrow) * Kd + lk * 8;
  f32x4 acc[4][2] = {};
  for (int kc = 0; kc < Kd; kc += 32) {
    bf16x8 ah[4], al[4], bh[2], bl[2];
#pragma unroll
    for (int f = 0; f < 4; ++f) {
      ah[f] = *reinterpret_cast<const bf16x8*>(ah0 + (size_t)f * 16 * Kd + kc);
      al[f] = *reinterpret_cast<const bf16x8*>(al0 + (size_t)f * 16 * Kd + kc);
    }
#pragma unroll
    for (int f = 0; f < 2; ++f) {
      bh[f] = *reinterpret_cast<const bf16x8*>(bh0 + (size_t)f * 16 * Kd + kc);
      bl[f] = *reinterpret_cast<const bf16x8*>(bl0 + (size_t)f * 16 * Kd + kc);
    }
#pragma unroll
    for (int rf = 0; rf < 4; ++rf)
#pragma unroll
      for (int cf = 0; cf < 2; ++cf) {
        acc[rf][cf] = __builtin_amdgcn_mfma_f32_16x16x32_bf16(ah[rf], bh[cf], acc[rf][cf], 0, 0, 0);
        acc[rf][cf] = __builtin_amdgcn_mfma_f32_16x16x32_bf16(al[rf], bh[cf], acc[rf][cf], 0, 0, 0);
        acc[rf][cf] = __builtin_amdgcn_mfma_f32_16x16x32_bf16(ah[rf], bl[cf], acc[rf][cf], 0, 0, 0);
      }
  }

  if (EPI == 0) {
#pragma unroll
    for (int rf = 0; rf < 4; ++rf)
#pragma unroll
      for (int cf = 0; cf < 2; ++cf) {
        int col = colb + cf * 16 + lrow;
        float bb = bias ? bias[col] : 0.f;
#pragma unroll
        for (int j = 0; j < 4; ++j) {
          int row = rowb + rf * 16 + lk * 4 + j;
          outf[(size_t)row * ldc + col] = acc[rf][cf][j] + bb;
        }
      }
  } else if (EPI == 1) {
    if (colb < D2) {   // whole 128-col block in norm region (bx 0..3)
      float ss[4][4] = {}, sc[4][4] = {};
#pragma unroll
      for (int cf = 0; cf < 2; ++cf) {
        int col = colb + cf * 16 + lrow;
        float bb = bias[col], bc = b2[col];
#pragma unroll
        for (int rf = 0; rf < 4; ++rf)
#pragma unroll
          for (int j = 0; j < 4; ++j) {
            float v = acc[rf][cf][j] + bb;
            ss[rf][j] = fmaf(v, v, ss[rf][j]);
            sc[rf][j] = fmaf(v, bc, sc[rf][j]);
          }
      }
#pragma unroll
      for (int rf = 0; rf < 4; ++rf)
#pragma unroll
        for (int j = 0; j < 4; ++j) {
          float a = ss[rf][j], c = sc[rf][j];
          a += __shfl_xor(a, 1); c += __shfl_xor(c, 1);
          a += __shfl_xor(a, 2); c += __shfl_xor(c, 2);
          a += __shfl_xor(a, 4); c += __shfl_xor(c, 4);
          a += __shfl_xor(a, 8); c += __shfl_xor(c, 8);
          if (lrow == 0) {
            int row = rowb + rf * 16 + lk * 4 + j;
            atomicAdd(&snacc[row], a);
            atomicAdd(&cacc[row], c);
          }
        }
    } else {
#pragma unroll
      for (int rf = 0; rf < 4; ++rf)
#pragma unroll
        for (int cf = 0; cf < 2; ++cf) {
          int col = colb + cf * 16 + lrow;
          float bb = bias[col];
#pragma unroll
          for (int j = 0; j < 4; ++j) {
            int row = rowb + rf * 16 + lk * 4 + j;
            float v = acc[rf][cf][j] + bb;
            if (col < D2 + G3) gh[(size_t)row * G3 + (col - D2)] = v;
            else               shat[(size_t)row * D2 + (col - (D2 + G3))] = v;
          }
        }
    }
  } else {  // EPI == 2: relu + o3 += relu(v) . w5 (per-wave partial)
#pragma unroll
    for (int rf = 0; rf < 4; ++rf)
#pragma unroll
      for (int j = 0; j < 4; ++j) {
        float p = 0.f;
#pragma unroll
        for (int cf = 0; cf < 2; ++cf) {
          int col = colb + cf * 16 + lrow;
          float v = fmaxf(acc[rf][cf][j] + bias[col], 0.f);
          p = fmaf(v, w5w[col], p);
        }
        p += __shfl_xor(p, 1); p += __shfl_xor(p, 2);
        p += __shfl_xor(p, 4); p += __shfl_xor(p, 8);
        if (lrow == 0) atomicAdd(&o3[rowb + rf * 16 + lk * 4 + j], p);
      }
  }
}

// ---------------- dot pass (bf16 m), reads norm accumulators ----------------
__global__ __launch_bounds__(256) void k_dot_bf(const ushort* __restrict__ mbf,
                                                const float* __restrict__ shat3,
                                                const float* __restrict__ norm2,
                                                const float* __restrict__ snacc,
                                                const float* __restrict__ cacc,
                                                const int* __restrict__ mask,
                                                float* __restrict__ att3) {
  __shared__ float sh[3][512];
  int b = blockIdx.x >> 3;
  int lt = blockIdx.x & 7;
  int tid = threadIdx.x;
  for (int k = 0; k < 3; ++k)
    for (int i = tid; i < 512; i += 256) sh[k][i] = shat3[(size_t)(k * B + b) * D2 + i];
  __syncthreads();
  int j = tid & 3, lidx = tid >> 2;
  int l = lt * 64 + lidx;
  const uint4* mrow = reinterpret_cast<const uint4*>(mbf + (size_t)(b * L + l) * D2);
  float a0 = 0.f, a1 = 0.f, a2 = 0.f;
#pragma unroll 4
  for (int s = 0; s < 16; ++s) {
    int c = s * 4 + j;
    uint4 mv = mrow[c];
    const float* p0 = &sh[0][c * 8];
    const float* p1 = &sh[1][c * 8];
    const float* p2 = &sh[2][c * 8];
    uint w[4] = {mv.x, mv.y, mv.z, mv.w};
#pragma unroll
    for (int q = 0; q < 4; ++q) {
      float lo = bflo(w[q]), hi = bfhi(w[q]);
      a0 = fmaf(lo, p0[q * 2], a0); a0 = fmaf(hi, p0[q * 2 + 1], a0);
      a1 = fmaf(lo, p1[q * 2], a1); a1 = fmaf(hi, p1[q * 2 + 1], a1);
      a2 = fmaf(lo, p2[q * 2], a2); a2 = fmaf(hi, p2[q * 2 + 1], a2);
    }
  }
  a0 += __shfl_xor(a0, 1); a0 += __shfl_xor(a0, 2);
  a1 += __shfl_xor(a1, 1); a1 += __shfl_xor(a1, 2);
  a2 += __shfl_xor(a2, 1); a2 += __shfl_xor(a2, 2);
  if (j == 0) {
    float mn = fmaxf(sqrtf(norm2[b * L + l]), EPSF);
    bool inv = (mask[b * L + l] == 0);
    float ar[3] = {a0, a1, a2};
#pragma unroll
    for (int k = 0; k < 3; ++k) {
      int r = k * B + b;
      float sn = fmaxf(sqrtf(snacc[r]), EPSF);
      float att = LAMDA * (ar[k] + cacc[r]) / (mn * sn);
      att3[(size_t)r * L + l] = inv ? -INFINITY : att;
    }
  }
}

// ---------------- fused softmax + f_att (raw att in, split planes out) ----------------
__global__ __launch_bounds__(256) void k_fatt_sm(const ushort* __restrict__ mbf,
                                                 const float* __restrict__ att3,
                                                 ushort* __restrict__ fatth,
                                                 ushort* __restrict__ fattl) {
  __shared__ float pp[3][512];
  __shared__ float red[3][256];
  __shared__ float inv3[3];
  int b = blockIdx.x >> 1, dt = blockIdx.x & 1;
  int tid = threadIdx.x;
  for (int k = 0; k < 3; ++k)
    for (int i = tid; i < 512; i += 256) pp[k][i] = att3[(size_t)(k * B + b) * L + i];
  __syncthreads();
  // softmax (unnormalized exp in pp, 1/sum in inv3) -- wave per branch
  int wv = tid >> 6, ln = tid & 63;
  if (wv < 3) {
    float x[8];
#pragma unroll
    for (int i = 0; i < 8; ++i) x[i] = pp[wv][ln + 64 * i];
    float mx = x[0];
#pragma unroll
    for (int i = 1; i < 8; ++i) mx = fmaxf(mx, x[i]);
    for (int o = 32; o; o >>= 1) mx = fmaxf(mx, __shfl_xor(mx, o));
    float e[8], s = 0.f;
#pragma unroll
    for (int i = 0; i < 8; ++i) { e[i] = expf(x[i] - mx); s += e[i]; }
    for (int o = 32; o; o >>= 1) s += __shfl_xor(s, o);
#pragma unroll
    for (int i = 0; i < 8; ++i) pp[wv][ln + 64 * i] = e[i];
    if (ln == 0) inv3[wv] = 1.0f / s;
  }
  __syncthreads();
  // f_att phase (scale by inv at the end)
  int dpair = tid & 127, half = tid >> 7;
  int d = dt * 256 + dpair * 2;
  float a[3][2] = {};
  int l0 = half * 256;
#pragma unroll 4
  for (int l = l0; l < l0 + 256; ++l) {
    uint w = *reinterpret_cast<const uint*>(&mbf[(size_t)(b * L + l) * D2 + d]);
    float f0 = bflo(w), f1 = bfhi(w);
#pragma unroll
    for (int k = 0; k < 3; ++k) {
      float p = pp[k][l];
      a[k][0] = fmaf(p, f0, a[k][0]);
      a[k][1] = fmaf(p, f1, a[k][1]);
    }
  }
  if (half == 1) {
#pragma unroll
    for (int k = 0; k < 3; ++k) { red[k][dpair * 2] = a[k][0]; red[k][dpair * 2 + 1] = a[k][1]; }
  }
  __syncthreads();
  if (half == 0) {
#pragma unroll
    for (int k = 0; k < 3; ++k) {
      float sc = inv3[k];
      float v0 = (a[k][0] + red[k][dpair * 2]) * sc;
      float v1 = (a[k][1] + red[k][dpair * 2 + 1]) * sc;
      ushort h0, l0u, h1, l1u;
      split2(v0, h0, l0u); split2(v1, h1, l1u);
      size_t o = (size_t)(k * B + b) * D2 + d;
      fatth[o] = h0;     fattl[o] = l0u;
      fatth[o + 1] = h1; fattl[o + 1] = l1u;
    }
  }
}

// ---------------- GRU gates (+ zero norm accumulators for next hop) ----------------
__global__ void k_gates(const float* __restrict__ gx, const float* __restrict__ gh,
                        float* __restrict__ st3,
                        ushort* __restrict__ sth, ushort* __restrict__ stl,
                        float* __restrict__ snacc, float* __restrict__ cacc) {
  int idx = blockIdx.x * blockDim.x + threadIdx.x;
  if (snacc && idx < R3) { snacc[idx] = 0.f; cacc[idx] = 0.f; }
  if (idx >= R3 * D4) return;
  int r = idx / D4, i = idx - r * D4;
  const float* gxr = gx + (size_t)r * G3;
  const float* ghr = gh + (size_t)r * G3;
  float xr = gxr[i], xz = gxr[D4 + i], xn = gxr[2 * D4 + i];
  float hr = ghr[i], hz = ghr[D4 + i], hn = ghr[2 * D4 + i];
  float rr = 1.f / (1.f + expf(-(xr + hr)));
  float zz = 1.f / (1.f + expf(-(xz + hz)));
  float nn = tanhf(xn + rr * hn);
  float h = st3[idx];
  float nv = (1.f - zz) * nn + zz * h;
  st3[idx] = nv;
  if (sth) { ushort hh, ll; split2(nv, hh, ll); sth[idx] = hh; stl[idx] = ll; }
}

// ---------------- final log_softmax ----------------
__global__ void k_final(const float* __restrict__ o3, const float* __restrict__ w5b,
                        float* __restrict__ out) {
  int b = threadIdx.x;
  if (b >= B) return;
  float v0 = o3[0 * B + b] + w5b[0];
  float v1 = o3[1 * B + b] + w5b[0];
  float v2 = o3[2 * B + b] + w5b[0];
  float mx = fmaxf(v0, fmaxf(v1, v2));
  float s = expf(v0 - mx) + expf(v1 - mx) + expf(v2 - mx);
  float lse = mx + logf(s);
  out[b * 3 + 0] = v0 - lse;
  out[b * 3 + 1] = v1 - lse;
  out[b * 3 + 2] = v2 - lse;
}

// ================= fallback f32 kernels (small-ws path) =================
__global__ __launch_bounds__(256) void k_mnorm(const float* __restrict__ m,
                                               const float* __restrict__ w2,
                                               const float* __restrict__ b2,
                                               float* __restrict__ norm2) {
  __shared__ float As[64][33];
  __shared__ float Ws[32][65];
  __shared__ float red[16][64];
  const int tid = threadIdx.x;
  const int ty = tid >> 4, tx = tid & 15;
  const long rowb = (long)blockIdx.x * 64;
  float rowpart[4] = {0.f, 0.f, 0.f, 0.f};
  for (int ct = 0; ct < 8; ++ct) {
    float acc[4][4] = {};
    for (int kc = 0; kc < 16; ++kc) {
#pragma unroll
      for (int i = 0; i < 8; ++i) {
        int li = tid + i * 256;
        int r = li >> 5, c = li & 31;
        As[r][c] = m[(rowb + r) * 512 + kc * 32 + c];
      }
#pragma unroll
      for (int i = 0; i < 8; ++i) {
        int li = tid + i * 256;
        int r = li >> 6, c = li & 63;
        Ws[r][c] = w2[(kc * 32 + r) * 512 + ct * 64 + c];
      }
      __syncthreads();
#pragma unroll
      for (int k = 0; k < 32; ++k) {
        float a[4], bb[4];
#pragma unroll
        for (int i = 0; i < 4; ++i) a[i] = As[ty * 4 + i][k];
#pragma unroll
        for (int jj = 0; jj < 4; ++jj) bb[jj] = Ws[k][tx * 4 + jj];
#pragma unroll
        for (int i = 0; i < 4; ++i)
#pragma unroll
          for (int jj = 0; jj < 4; ++jj) acc[i][jj] = fmaf(a[i], bb[jj], acc[i][jj]);
      }
      __syncthreads();
    }
#pragma unroll
    for (int jj = 0; jj < 4; ++jj) {
      float bj = b2[ct * 64 + tx * 4 + jj];
#pragma unroll
      for (int i = 0; i < 4; ++i) {
        float v = acc[i][jj] + bj;
        rowpart[i] = fmaf(v, v, rowpart[i]);
      }
    }
  }
#pragma unroll
  for (int i = 0; i < 4; ++i) red[tx][ty * 4 + i] = rowpart[i];
  __syncthreads();
  if (tid < 64) {
    float s = 0.f;
#pragma unroll
    for (int t = 0; t < 16; ++t) s += red[t][tid];
    norm2[rowb + tid] = s;
  }
}

template <bool BT, int ACT>
__global__ __launch_bounds__(256) void k_gemm64(const float* __restrict__ A, int lda,
                                                const float* __restrict__ Bm, int ldb,
                                                const float* __restrict__ bias,
                                                float* __restrict__ C, int ldc, int Kd) {
  __shared__ float As[64][33];
  __shared__ float Bs[32][65];
  const int tid = threadIdx.x;
  const int ty = tid >> 4, tx = tid & 15;
  const int rowb = blockIdx.y * 64;
  const int colb = blockIdx.x * 64;
  float acc[4][4] = {};
  for (int kc = 0; kc < Kd; kc += 32) {
#pragma unroll
    for (int i = 0; i < 8; ++i) {
      int li = tid + i * 256;
      int r = li >> 5, c = li & 31;
      As[r][c] = A[(long)(rowb + r) * lda + kc + c];
    }
    if (!BT) {
#pragma unroll
      for (int i = 0; i < 8; ++i) {
        int li = tid + i * 256;
        int r = li >> 6, c = li & 63;
        Bs[r][c] = Bm[(long)(kc + r) * ldb + colb + c];
      }
    } else {
#pragma unroll
      for (int i = 0; i < 8; ++i) {
        int li = tid + i * 256;
        int n = li >> 5, k = li & 31;
        Bs[k][n] = Bm[(long)(colb + n) * ldb + kc + k];
      }
    }
    __syncthreads();
#pragma unroll
    for (int k = 0; k < 32; ++k) {
      float a[4], bb[4];
#pragma unroll
      for (int i = 0; i < 4; ++i) a[i] = As[ty * 4 + i][k];
#pragma unroll
      for (int jj = 0; jj < 4; ++jj) bb[jj] = Bs[k][tx * 4 + jj];
#pragma unroll
      for (int i = 0; i < 4; ++i)
#pragma unroll
        for (int jj = 0; jj < 4; ++jj) acc[i][jj] = fmaf(a[i], bb[jj], acc[i][jj]);
    }
    __syncthreads();
  }
#pragma unroll
  for (int i = 0; i < 4; ++i) {
    int row = rowb + ty * 4 + i;
#pragma unroll
    for (int jj = 0; jj < 4; ++jj) {
      int col = colb + tx * 4 + jj;
      float v = acc[i][jj];
      if (bias) v += bias[col];
      if (ACT == 1) v = fmaxf(v, 0.f);
      C[(long)row * ldc + col] = v;
    }
  }
}

__global__ void k_snorm(const float* __restrict__ stt3, const float* __restrict__ b2,
                        float* __restrict__ sn3, float* __restrict__ c3) {
  int r = blockIdx.x;
  int tid = threadIdx.x;
  float ss = 0.f, sc = 0.f;
  for (int j = tid; j < D2; j += 256) {
    float v = stt3[(size_t)r * D2 + j];
    ss = fmaf(v, v, ss);
    sc = fmaf(v, b2[j], sc);
  }
  for (int o = 32; o; o >>= 1) {
    ss += __shfl_down(ss, o);
    sc += __shfl_down(sc, o);
  }
  __shared__ float rs[4], rc[4];
  int w = tid >> 6;
  if ((tid & 63) == 0) { rs[w] = ss; rc[w] = sc; }
  __syncthreads();
  if (tid == 0) {
    sn3[r] = fmaxf(sqrtf(rs[0] + rs[1] + rs[2] + rs[3]), EPSF);
    c3[r] = rc[0] + rc[1] + rc[2] + rc[3];
  }
}

__global__ __launch_bounds__(256) void k_dot(const float* __restrict__ m,
                                             const float* __restrict__ shat3,
                                             const float* __restrict__ norm2,
                                             const float* __restrict__ sn3,
                                             const float* __restrict__ c3,
                                             const int* __restrict__ mask,
                                             float* __restrict__ att3) {
  __shared__ float sh[3][512];
  int b = blockIdx.x >> 3;
  int lt = blockIdx.x & 7;
  int tid = threadIdx.x;
  for (int k = 0; k < 3; ++k)
    for (int i = tid; i < 512; i += 256) sh[k][i] = shat3[(size_t)(k * B + b) * D2 + i];
  __syncthreads();
  int j = tid & 3, lidx = tid >> 2;
  int l = lt * 64 + lidx;
  const float4* mrow = reinterpret_cast<const float4*>(m + (size_t)(b * L + l) * D2);
  float a0 = 0.f, a1 = 0.f, a2 = 0.f;
#pragma unroll 8
  for (int s = 0; s < 32; ++s) {
    int d4 = s * 4 + j;
    float4 mv = mrow[d4];
    const float4 v0 = *reinterpret_cast<const float4*>(&sh[0][d4 * 4]);
    const float4 v1 = *reinterpret_cast<const float4*>(&sh[1][d4 * 4]);
    const float4 v2 = *reinterpret_cast<const float4*>(&sh[2][d4 * 4]);
    a0 += mv.x * v0.x + mv.y * v0.y + mv.z * v0.z + mv.w * v0.w;
    a1 += mv.x * v1.x + mv.y * v1.y + mv.z * v1.z + mv.w * v1.w;
    a2 += mv.x * v2.x + mv.y * v2.y + mv.z * v2.z + mv.w * v2.w;
  }
  a0 += __shfl_xor(a0, 1); a0 += __shfl_xor(a0, 2);
  a1 += __shfl_xor(a1, 1); a1 += __shfl_xor(a1, 2);
  a2 += __shfl_xor(a2, 1); a2 += __shfl_xor(a2, 2);
  if (j == 0) {
    float mn = fmaxf(sqrtf(norm2[b * L + l]), EPSF);
    bool inv = (mask[b * L + l] == 0);
    float ar[3] = {a0, a1, a2};
#pragma unroll
    for (int k = 0; k < 3; ++k) {
      int r = k * B + b;
      float att = LAMDA * (ar[k] + c3[r]) / (mn * sn3[r]);
      att3[(size_t)r * L + l] = inv ? -INFINITY : att;
    }
  }
}

__global__ void k_softmax(float* __restrict__ att3) {
  int r = blockIdx.x;
  float* row = att3 + (size_t)r * L;
  int tid = threadIdx.x;
  float x0 = row[tid], x1 = row[tid + 256];
  float mx = fmaxf(x0, x1);
  for (int o = 32; o; o >>= 1) mx = fmaxf(mx, __shfl_xor(mx, o));
  __shared__ float rm[4], rs[4];
  int w = tid >> 6;
  if ((tid & 63) == 0) rm[w] = mx;
  __syncthreads();
  mx = fmaxf(fmaxf(rm[0], rm[1]), fmaxf(rm[2], rm[3]));
  float e0 = expf(x0 - mx), e1 = expf(x1 - mx);
  float s = e0 + e1;
  for (int o = 32; o; o >>= 1) s += __shfl_xor(s, o);
  if ((tid & 63) == 0) rs[w] = s;
  __syncthreads();
  s = rs[0] + rs[1] + rs[2] + rs[3];
  float inv = 1.0f / s;
  row[tid] = e0 * inv;
  row[tid + 256] = e1 * inv;
}

__global__ __launch_bounds__(256) void k_fatt(const float* __restrict__ m,
                                              const float* __restrict__ p3,
                                              float* __restrict__ fatt3) {
  __shared__ float pp[3][512];
  __shared__ float red[3][128];
  int b = blockIdx.x >> 2, dt = blockIdx.x & 3;
  int tid = threadIdx.x;
  for (int k = 0; k < 3; ++k)
    for (int i = tid; i < 512; i += 256) pp[k][i] = p3[(size_t)(k * B + b) * L + i];
  __syncthreads();
  int d = dt * 128 + (tid & 127);
  int half = tid >> 7;
  float a0 = 0.f, a1 = 0.f, a2 = 0.f;
  int l0 = half * 256;
  for (int l = l0; l < l0 + 256; ++l) {
    float mv = m[(size_t)(b * L + l) * D2 + d];
    a0 = fmaf(pp[0][l], mv, a0);
    a1 = fmaf(pp[1][l], mv, a1);
    a2 = fmaf(pp[2][l], mv, a2);
  }
  int dd = tid & 127;
  if (half == 1) { red[0][dd] = a0; red[1][dd] = a1; red[2][dd] = a2; }
  __syncthreads();
  if (half == 0) {
    fatt3[(size_t)(0 * B + b) * D2 + d] = a0 + red[0][dd];
    fatt3[(size_t)(1 * B + b) * D2 + d] = a1 + red[1][dd];
    fatt3[(size_t)(2 * B + b) * D2 + d] = a2 + red[2][dd];
  }
}

__global__ void k_w5(const float* __restrict__ h4, const float* __restrict__ w5w,
                     float* __restrict__ o3) {
  int r = blockIdx.x, tid = threadIdx.x;
  float s = 0.f;
  for (int d = tid; d < D4; d += 256) s = fmaf(h4[(size_t)r * D4 + d], w5w[d], s);
  for (int o = 32; o; o >>= 1) s += __shfl_down(s, o);
  __shared__ float rs[4];
  if ((tid & 63) == 0) rs[tid >> 6] = s;
  __syncthreads();
  if (tid == 0) o3[r] = rs[0] + rs[1] + rs[2] + rs[3];
}

extern "C" void kernel_launch(void* const* d_in, const int* in_sizes, int n_in,
                              void* d_out, int out_size, void* d_ws, size_t ws_size,
                              hipStream_t stream) {
  const float* m    = (const float*)d_in[0];
  const float* s1   = (const float*)d_in[1];
  const float* s2   = (const float*)d_in[2];
  const float* s3   = (const float*)d_in[3];
  const int*   mask = (const int*)d_in[4];
  const float* w2w  = (const float*)d_in[5];
  const float* w2b  = (const float*)d_in[6];
  const float* w3w  = (const float*)d_in[7];
  const float* w3b  = (const float*)d_in[8];
  const float* w4w  = (const float*)d_in[9];
  const float* w4b  = (const float*)d_in[10];
  const float* w5w  = (const float*)d_in[11];
  const float* w5b  = (const float*)d_in[12];
  const float* gwi  = (const float*)d_in[13];
  const float* gwh  = (const float*)d_in[14];
  const float* gbi  = (const float*)d_in[15];
  const float* gbh  = (const float*)d_in[16];
  float* out = (float*)d_out;

  float* ws = (float*)d_ws;
  size_t off = 0;
  auto alloc = [&](size_t n) {
    float* p = ws + off;
    off += (n + 63) & ~(size_t)63;
    return p;
  };
  ushort* mbf   = (ushort*)alloc((size_t)B * L * D2 / 2);
  ushort* w2t   = (ushort*)alloc((size_t)D2 * D2 / 2);
  ushort* catBh = (ushort*)alloc((size_t)NC * D4 / 2);
  ushort* catBl = (ushort*)alloc((size_t)NC * D4 / 2);
  ushort* gxBh  = (ushort*)alloc((size_t)G3 * D2 / 2);
  ushort* gxBl  = (ushort*)alloc((size_t)G3 * D2 / 2);
  ushort* w4Bh  = (ushort*)alloc((size_t)D4 * D4 / 2);
  ushort* w4Bl  = (ushort*)alloc((size_t)D4 * D4 / 2);
  float* bcat   = alloc(NC);
  float* norm2  = alloc((size_t)B * L);
  float* st3    = alloc((size_t)R3 * D4);
  ushort* sth   = (ushort*)alloc((size_t)R3 * D4 / 2);
  ushort* stl   = (ushort*)alloc((size_t)R3 * D4 / 2);
  float* shat3  = alloc((size_t)R3 * D2);
  float* snacc  = alloc(R3);
  float* cacc   = alloc(R3);
  float* o3     = alloc(R3);
  ushort* fatth = (ushort*)alloc((size_t)R3 * D2 / 2);
  ushort* fattl = (ushort*)alloc((size_t)R3 * D2 / 2);
  float* att3   = alloc((size_t)R3 * L);
  float* gx     = alloc((size_t)R3 * G3);
  float* gh     = alloc((size_t)R3 * G3);
  const size_t big_need = off;
  const bool big = ws_size >= big_need * sizeof(float);

  if (big) {
    ushort* w2dh = (ushort*)gh;
    ushort* w2dl = w2dh + (size_t)D2 * D2;
    ushort* w3dh = (ushort*)gx;
    ushort* w3dl = w3dh + (size_t)D4 * D2;

    k_init<<<1536, 256, 0, stream>>>(s1, s2, s3, st3, sth, stl, snacc, cacc, o3);
    k_conv_m<<<2048, 256, 0, stream>>>(m, mbf);
    k_w2t<<<64, 256, 0, stream>>>(w2w, w2t);
    k_mnorm4<<<(B * L) / 64, 256, 0, stream>>>(mbf, w2t, w2b, norm2);
    k_split_trans<<<dim3(D4 / 64, D2 / 64), 256, 0, stream>>>(w3w, D4, D2, catBh, catBl);
    k_split_direct<<<1024, 256, 0, stream>>>(gwh, catBh + (size_t)D2 * D4, catBl + (size_t)D2 * D4,
                                             (G3 * D4) / 4);
    k_split_direct<<<512, 256, 0, stream>>>(gwi, gxBh, gxBl, (G3 * D2) / 4);
    k_split_trans<<<dim3(D4 / 64, D4 / 64), 256, 0, stream>>>(w4w, D4, D4, w4Bh, w4Bl);
    k_split_direct<<<256, 256, 0, stream>>>(w2w, w2dh, w2dl, (D2 * D2) / 4);
    k_split_direct<<<256, 256, 0, stream>>>(w3w, w3dh, w3dl, (D4 * D2) / 4);
    k_bcat2<<<16, 256, 0, stream>>>(w3b, gbh, w2w, bcat);
    k_gemm_wf<<<dim3(D4 / 64, D2 / 64), 64, 0, stream>>>(
        w2dh, w2dl, w3dh, w3dl,
        catBh + (size_t)(D2 + G3) * D4, catBl + (size_t)(D2 + G3) * D4);

    for (int hop = 0; hop < 3; ++hop) {
      k_gemm6<1><<<dim3(NC / 128, R3 / 64), 256, 0, stream>>>(
          sth, stl, catBh, catBl, D4, bcat, nullptr, 0,
          gh, shat3, snacc, cacc, w2b, nullptr, nullptr);
      k_dot_bf<<<B * 8, 256, 0, stream>>>(mbf, shat3, norm2, snacc, cacc, mask, att3);
      k_fatt_sm<<<B * 2, 256, 0, stream>>>(mbf, att3, fatth, fattl);
      k_gemm6<0><<<dim3(G3 / 128, R3 / 64), 256, 0, stream>>>(
          fatth, fattl, gxBh, gxBl, D2, gbi, gx, G3,
          nullptr, nullptr, nullptr, nullptr, nullptr, nullptr, nullptr);
      k_gates<<<1536, 256, 0, stream>>>(gx, gh, st3, sth, stl, snacc, cacc);
    }
    k_gemm6<2><<<dim3(D4 / 128, R3 / 64), 256, 0, stream>>>(
        sth, stl, w4Bh, w4Bl, D4, w4b, nullptr, 0,
        nullptr, nullptr, nullptr, nullptr, nullptr, w5w, o3);
    k_final<<<1, 128, 0, stream>>>(o3, w5b, out);
  } else {
    off = 0;
    float* f_st3   = alloc((size_t)R3 * D4);
    float* f_norm2 = alloc((size_t)B * L);
    float* f_stt   = alloc((size_t)R3 * D2);
    float* f_shat  = alloc((size_t)R3 * D2);
    float* f_sn    = alloc(R3);
    float* f_c     = alloc(R3);
    float* f_att   = alloc((size_t)R3 * L);
    float* f_fatt  = alloc((size_t)R3 * D2);
    float* f_gx    = alloc((size_t)R3 * G3);
    float* f_gh    = alloc((size_t)R3 * G3);
    float* f_h4    = alloc((size_t)R3 * D4);
    float* f_o3    = alloc(R3);
    k_init<<<1536, 256, 0, stream>>>(s1, s2, s3, f_st3, nullptr, nullptr, f_sn, f_c, f_o3);
    k_mnorm<<<(B * L) / 64, 256, 0, stream>>>(m, w2w, w2b, f_norm2);
    for (int hop = 0; hop < 3; ++hop) {
      k_gemm64<false, 0><<<dim3(D2 / 64, R3 / 64), 256, 0, stream>>>(f_st3, D4, w3w, D2, w3b, f_stt, D2, D4);
      k_snorm<<<R3, 256, 0, stream>>>(f_stt, w2b, f_sn, f_c);
      k_gemm64<true, 0><<<dim3(D2 / 64, R3 / 64), 256, 0, stream>>>(f_stt, D2, w2w, D2, nullptr, f_shat, D2, D2);
      k_dot<<<B * 8, 256, 0, stream>>>(m, f_shat, f_norm2, f_sn, f_c, mask, f_att);
      k_softmax<<<3 * B, 256, 0, stream>>>(f_att);
      k_fatt<<<B * 4, 256, 0, stream>>>(m, f_att, f_fatt);
      k_gemm64<true, 0><<<dim3(G3 / 64, R3 / 64), 256, 0, stream>>>(f_fatt, D2, gwi, D2, gbi, f_gx, G3, D2);
      k_gemm64<true, 0><<<dim3(G3 / 64, R3 / 64), 256, 0, stream>>>(f_st3, D4, gwh, D4, gbh, f_gh, G3, D4);
      k_gates<<<1536, 256, 0, stream>>>(f_gx, f_gh, f_st3, nullptr, nullptr, nullptr, nullptr);
    }
    k_gemm64<false, 1><<<dim3(D4 / 64, R3 / 64), 256, 0, stream>>>(f_st3, D4, w4w, D4, w4b, f_h4, D4, D4);
    k_w5<<<R3, 256, 0, stream>>>(f_h4, w5w, f_o3);
    k_final<<<1, 128, 0, stream>>>(f_o3, w5b, out);
  }
}

// Round 11
// 465.816 us; speedup vs baseline: 1.3166x; 1.3166x over previous
//
#include <hip/hip_runtime.h>
#include <math.h>

constexpr int B  = 128;
constexpr int L  = 512;
constexpr int D2 = 512;    // 2H
constexpr int D4 = 1024;   // 4H
constexpr int G3 = 3072;   // 3*4H
constexpr int R3 = 384;    // 3*B (branch-major rows: r = k*B + b)
constexpr int NC = 4096;   // cat N: [0,512) stt(norm only) | [512,3584) gh | [3584,4096) shat
constexpr float LAMDA = 3.0f;
constexpr float EPSF  = 1e-8f;

typedef __attribute__((ext_vector_type(8))) short bf16x8;
typedef __attribute__((ext_vector_type(8))) short short8;
typedef __attribute__((ext_vector_type(4))) float f32x4;

__device__ __forceinline__ ushort f2bf(float v) {
  uint u = __builtin_bit_cast(uint, v);
  u = (u + 0x7fffu + ((u >> 16) & 1u)) >> 16;   // RNE
  return (ushort)u;
}
__device__ __forceinline__ float bf2f(ushort h) {
  return __builtin_bit_cast(float, (uint)h << 16);
}
__device__ __forceinline__ float bflo(uint w) { return __builtin_bit_cast(float, w << 16); }
__device__ __forceinline__ float bfhi(uint w) { return __builtin_bit_cast(float, w & 0xffff0000u); }
__device__ __forceinline__ void split2(float v, ushort& h, ushort& l) {
  h = f2bf(v);
  l = f2bf(v - bf2f(h));
}
// async global->LDS, 16B per lane; LDS dest = wave-uniform base + lane*16
__device__ __forceinline__ void gload_lds16(const void* g, void* l) {
  __builtin_amdgcn_global_load_lds(
      (const __attribute__((address_space(1))) unsigned int*)g,
      (__attribute__((address_space(3))) unsigned int*)l, 16, 0, 0);
}

// ---------------- init ----------------
__global__ void k_init(const float* __restrict__ s1, const float* __restrict__ s2,
                       const float* __restrict__ s3, float* __restrict__ st3,
                       ushort* __restrict__ sth, ushort* __restrict__ stl,
                       float* __restrict__ snacc, float* __restrict__ cacc,
                       float* __restrict__ o3) {
  int idx = blockIdx.x * blockDim.x + threadIdx.x;
  if (idx < R3) { snacc[idx] = 0.f; cacc[idx] = 0.f; o3[idx] = 0.f; }
  int total = R3 * D4;
  for (; idx < total; idx += gridDim.x * blockDim.x) {
    int r = idx / D4, i = idx - r * D4;
    int k = r / B, b = r - k * B;
    const float* s = (k == 0) ? s1 : (k == 1) ? s2 : s3;
    float v = s[b * D4 + i];
    st3[idx] = v;
    if (sth) { ushort h, l; split2(v, h, l); sth[idx] = h; stl[idx] = l; }
  }
}

// ---------------- conversions ----------------
__global__ void k_conv_m(const float* __restrict__ m, ushort* __restrict__ mbf) {
  int idx = blockIdx.x * blockDim.x + threadIdx.x;
  const int total8 = (B * L * D2) / 8;
  for (; idx < total8; idx += gridDim.x * blockDim.x) {
    const float4* p = reinterpret_cast<const float4*>(m) + (size_t)idx * 2;
    float4 a = p[0], c = p[1];
    ushort o[8] = {f2bf(a.x), f2bf(a.y), f2bf(a.z), f2bf(a.w),
                   f2bf(c.x), f2bf(c.y), f2bf(c.z), f2bf(c.w)};
    *reinterpret_cast<uint4*>(mbf + (size_t)idx * 8) = *reinterpret_cast<const uint4*>(o);
  }
}

__global__ void k_w2t(const float* __restrict__ w2, ushort* __restrict__ w2t) {
  __shared__ ushort t[64][65];
  int bk = (blockIdx.x & 7) * 64, bn = (blockIdx.x >> 3) * 64;
  int tid = threadIdx.x;
#pragma unroll
  for (int i = 0; i < 16; ++i) {
    int e = tid + i * 256; int r = e >> 6, c = e & 63;
    t[r][c] = f2bf(w2[(bk + r) * 512 + bn + c]);
  }
  __syncthreads();
#pragma unroll
  for (int i = 0; i < 16; ++i) {
    int e = tid + i * 256; int r = e >> 6, c = e & 63;
    w2t[(bn + r) * 512 + bk + c] = t[c][r];
  }
}

__device__ __forceinline__ void split_f4(const float* in, ushort* oh, ushort* ol, int j) {
  float4 v = reinterpret_cast<const float4*>(in)[j];
  ushort4 h, l;
  split2(v.x, h.x, l.x); split2(v.y, h.y, l.y);
  split2(v.z, h.z, l.z); split2(v.w, h.w, l.w);
  reinterpret_cast<ushort4*>(oh)[j] = h;
  reinterpret_cast<ushort4*>(ol)[j] = l;
}

// fused 4-way direct split (gwh->catB tail, gwi->gxB, w2->w2d, w3->w3d)
__global__ void k_split4(const float* __restrict__ i0, ushort* __restrict__ h0, ushort* __restrict__ l0, int n0,
                         const float* __restrict__ i1, ushort* __restrict__ h1, ushort* __restrict__ l1, int n1,
                         const float* __restrict__ i2, ushort* __restrict__ h2, ushort* __restrict__ l2, int n2,
                         const float* __restrict__ i3, ushort* __restrict__ h3, ushort* __restrict__ l3, int n3) {
  int idx = blockIdx.x * blockDim.x + threadIdx.x;
  int ntot = n0 + n1 + n2 + n3;
  for (; idx < ntot; idx += gridDim.x * blockDim.x) {
    int j = idx;
    if (j < n0) { split_f4(i0, h0, l0, j); continue; }
    j -= n0;
    if (j < n1) { split_f4(i1, h1, l1, j); continue; }
    j -= n1;
    if (j < n2) { split_f4(i2, h2, l2, j); continue; }
    j -= n2;
    split_f4(i3, h3, l3, j);
  }
}

__global__ void k_split_trans(const float* __restrict__ in, int K, int N,
                              ushort* __restrict__ oh, ushort* __restrict__ ol) {
  __shared__ float t[64][65];
  int bk = blockIdx.x * 64, bn = blockIdx.y * 64;
  int tid = threadIdx.x;
#pragma unroll
  for (int i = 0; i < 16; ++i) {
    int e = tid + i * 256; int r = e >> 6, c = e & 63;
    t[r][c] = in[(size_t)(bk + r) * N + bn + c];
  }
  __syncthreads();
#pragma unroll
  for (int i = 0; i < 16; ++i) {
    int e = tid + i * 256; int r = e >> 6, c = e & 63;
    ushort h, l;
    split2(t[c][r], h, l);
    oh[(size_t)(bn + r) * K + bk + c] = h;
    ol[(size_t)(bn + r) * K + bk + c] = l;
  }
}

__global__ void k_bcat2(const float* __restrict__ w3b, const float* __restrict__ gbh,
                        const float* __restrict__ w2w, float* __restrict__ bcat) {
  int idx = blockIdx.x * 256 + threadIdx.x;
  if (idx < D2) bcat[idx] = w3b[idx];
  else if (idx < D2 + G3) bcat[idx] = gbh[idx - D2];
  else if (idx < NC) {
    int e = idx - (D2 + G3);
    float s = 0.f;
    for (int d = 0; d < D2; ++d) s = fmaf(w3b[d], w2w[(size_t)e * D2 + d], s);
    bcat[idx] = s;
  }
}

// ---------------- one-time: WfT[e][q] = dot(w2 row e, w3 row q) ----------------
__global__ __launch_bounds__(64) void k_gemm_wf(
    const ushort* __restrict__ Ahp, const ushort* __restrict__ Alp,
    const ushort* __restrict__ Bhp, const ushort* __restrict__ Blp,
    ushort* __restrict__ Ch, ushort* __restrict__ Cl) {
  const int ln = threadIdx.x;
  const int lrow = ln & 15, lk = ln >> 4;
  const int rowb = blockIdx.y * 64;
  const int colb = blockIdx.x * 64;
  size_t aoff[4], boff[4];
#pragma unroll
  for (int f = 0; f < 4; ++f) {
    aoff[f] = (size_t)(rowb + f * 16 + lrow) * D2 + lk * 8;
    boff[f] = (size_t)(colb + f * 16 + lrow) * D2 + lk * 8;
  }
  f32x4 acc[4][4] = {};
  for (int kc = 0; kc < D2; kc += 32) {
    bf16x8 ah[4], al[4], bh[4], bl[4];
#pragma unroll
    for (int f = 0; f < 4; ++f) {
      ah[f] = *reinterpret_cast<const bf16x8*>(Ahp + aoff[f] + kc);
      al[f] = *reinterpret_cast<const bf16x8*>(Alp + aoff[f] + kc);
      bh[f] = *reinterpret_cast<const bf16x8*>(Bhp + boff[f] + kc);
      bl[f] = *reinterpret_cast<const bf16x8*>(Blp + boff[f] + kc);
    }
#pragma unroll
    for (int rf = 0; rf < 4; ++rf)
#pragma unroll
      for (int cf = 0; cf < 4; ++cf) {
        acc[rf][cf] = __builtin_amdgcn_mfma_f32_16x16x32_bf16(ah[rf], bh[cf], acc[rf][cf], 0, 0, 0);
        acc[rf][cf] = __builtin_amdgcn_mfma_f32_16x16x32_bf16(al[rf], bh[cf], acc[rf][cf], 0, 0, 0);
        acc[rf][cf] = __builtin_amdgcn_mfma_f32_16x16x32_bf16(ah[rf], bl[cf], acc[rf][cf], 0, 0, 0);
      }
  }
#pragma unroll
  for (int rf = 0; rf < 4; ++rf)
#pragma unroll
    for (int cf = 0; cf < 4; ++cf) {
      int col = colb + cf * 16 + lrow;
#pragma unroll
      for (int j = 0; j < 4; ++j) {
        int row = rowb + rf * 16 + lk * 4 + j;
        ushort h, l;
        split2(acc[rf][cf][j], h, l);
        Ch[(size_t)row * D4 + col] = h;
        Cl[(size_t)row * D4 + col] = l;
      }
    }
}

// ---------------- m_norm^4: LDS-staged MFMA (validated R7) ----------------
__global__ __launch_bounds__(256, 2) void k_mnorm4(const ushort* __restrict__ mbf,
                                                   const ushort* __restrict__ w2t,
                                                   const float* __restrict__ b2,
                                                   float* __restrict__ norm2) {
  __shared__ ushort As[2][64 * 32];
  __shared__ ushort Bs[2][512 * 32];
  const int tid = threadIdx.x;
  const int wv = tid >> 6, ln = tid & 63;
  const int lrow = ln & 15, lk = ln >> 4;
  const size_t rowb = (size_t)blockIdx.x * 64;

  auto stage = [&](int buf, int kc) {
    {
      int li = wv * 64 + ln;
      int row = li >> 2, slot = li & 3;
      const ushort* src = mbf + (rowb + row) * 512 + kc + ((slot ^ (row & 3)) << 3);
      gload_lds16(src, &As[buf][(size_t)wv * 64 * 8]);
    }
#pragma unroll
    for (int i = 0; i < 8; ++i) {
      int c = wv * 8 + i;
      int li = c * 64 + ln;
      int col = li >> 2, slot = li & 3;
      const ushort* src = w2t + (size_t)col * 512 + kc + ((slot ^ (col & 3)) << 3);
      gload_lds16(src, &Bs[buf][(size_t)c * 64 * 8]);
    }
  };

  f32x4 acc[4][8] = {};
  stage(0, 0);
  __syncthreads();
  for (int t = 0; t < 16; ++t) {
    int cur = t & 1;
    if (t + 1 < 16) stage(cur ^ 1, (t + 1) * 32);
    bf16x8 af[4], bfr[8];
#pragma unroll
    for (int rf = 0; rf < 4; ++rf) {
      int row = rf * 16 + lrow;
      af[rf] = *reinterpret_cast<const bf16x8*>(&As[cur][row * 32 + ((lk ^ (row & 3)) << 3)]);
    }
#pragma unroll
    for (int cf = 0; cf < 8; ++cf) {
      int col = wv * 128 + cf * 16 + lrow;
      bfr[cf] = *reinterpret_cast<const bf16x8*>(&Bs[cur][col * 32 + ((lk ^ (col & 3)) << 3)]);
    }
#pragma unroll
    for (int rf = 0; rf < 4; ++rf)
#pragma unroll
      for (int cf = 0; cf < 8; ++cf)
        acc[rf][cf] = __builtin_amdgcn_mfma_f32_16x16x32_bf16(af[rf], bfr[cf], acc[rf][cf], 0, 0, 0);
    __syncthreads();
  }

  float nrm[4][4] = {};
#pragma unroll
  for (int cf = 0; cf < 8; ++cf) {
    float bb = b2[wv * 128 + cf * 16 + lrow];
#pragma unroll
    for (int rf = 0; rf < 4; ++rf)
#pragma unroll
      for (int j = 0; j < 4; ++j) {
        float v = acc[rf][cf][j] + bb;
        nrm[rf][j] = fmaf(v, v, nrm[rf][j]);
      }
  }
  __shared__ float red[4][64];
#pragma unroll
  for (int rf = 0; rf < 4; ++rf)
#pragma unroll
    for (int j = 0; j < 4; ++j) {
      float v = nrm[rf][j];
      v += __shfl_xor(v, 1); v += __shfl_xor(v, 2);
      v += __shfl_xor(v, 4); v += __shfl_xor(v, 8);
      if (lrow == 0) red[wv][rf * 16 + lk * 4 + j] = v;
    }
  __syncthreads();
  if (tid < 64)
    norm2[rowb + tid] = red[0][tid] + red[1][tid] + red[2][tid] + red[3][tid];
}

// ---------------- k_gemm5: split-K 4-wave GEMM (32x64 tile) -- R9 best ----------------
#define G3_LOAD(AH_, AL_, BH_, BL_, KC_)                                                    \
  do {                                                                                      \
    _Pragma("unroll") for (int f = 0; f < 2; ++f) {                                         \
      AH_[f] = *reinterpret_cast<const bf16x8*>(ah0 + (size_t)f * 16 * Kd + (KC_));         \
      AL_[f] = *reinterpret_cast<const bf16x8*>(al0 + (size_t)f * 16 * Kd + (KC_));         \
    }                                                                                       \
    _Pragma("unroll") for (int f = 0; f < 4; ++f) {                                         \
      BH_[f] = *reinterpret_cast<const bf16x8*>(bh0 + (size_t)f * 16 * Kd + (KC_));         \
      BL_[f] = *reinterpret_cast<const bf16x8*>(bl0 + (size_t)f * 16 * Kd + (KC_));         \
    }                                                                                       \
  } while (0)
#define G3_MFMA(AH_, AL_, BH_, BL_)                                                         \
  do {                                                                                      \
    _Pragma("unroll") for (int rf = 0; rf < 2; ++rf)                                        \
        _Pragma("unroll") for (int cf = 0; cf < 4; ++cf) {                                  \
      acc[rf][cf] = __builtin_amdgcn_mfma_f32_16x16x32_bf16(AH_[rf], BH_[cf], acc[rf][cf],  \
                                                            0, 0, 0);                       \
      acc[rf][cf] = __builtin_amdgcn_mfma_f32_16x16x32_bf16(AL_[rf], BH_[cf], acc[rf][cf],  \
                                                            0, 0, 0);                       \
      acc[rf][cf] = __builtin_amdgcn_mfma_f32_16x16x32_bf16(AH_[rf], BL_[cf], acc[rf][cf],  \
                                                            0, 0, 0);                       \
    }                                                                                       \
  } while (0)

// EPI 0: outf = A@B + bias | EPI 1: cat (norm atomics | gh | shat) | EPI 2: relu + w5 atomics
template <int EPI>
__global__ __launch_bounds__(256) void k_gemm5(
    const ushort* __restrict__ Ahp, const ushort* __restrict__ Alp,
    const ushort* __restrict__ Bhp, const ushort* __restrict__ Blp,
    int Kd, const float* __restrict__ bias,
    float* __restrict__ outf, int ldc,
    float* __restrict__ gh, float* __restrict__ shat,
    float* __restrict__ snacc, float* __restrict__ cacc,
    const float* __restrict__ b2,
    const float* __restrict__ w5w, float* __restrict__ o3) {
  __shared__ float red[3][32][64];   // [wave-1][elem][lane] -> conflict-free
  const int tid = threadIdx.x;
  const int wv = tid >> 6, ln = tid & 63;
  const int lrow = ln & 15, lk = ln >> 4;
  const int rowb = blockIdx.y * 32;
  const int colb = blockIdx.x * 64;
  const int Ks = Kd >> 2;            // per-wave K slice
  const int koff = wv * Ks;
  const ushort* ah0 = Ahp + (size_t)(rowb + lrow) * Kd + koff + lk * 8;
  const ushort* al0 = Alp + (size_t)(rowb + lrow) * Kd + koff + lk * 8;
  const ushort* bh0 = Bhp + (size_t)(colb + lrow) * Kd + koff + lk * 8;
  const ushort* bl0 = Blp + (size_t)(colb + lrow) * Kd + koff + lk * 8;
  f32x4 acc[2][4] = {};
  bf16x8 ahA[2], alA[2], bhA[4], blA[4];
  bf16x8 ahB[2], alB[2], bhB[4], blB[4];
  G3_LOAD(ahA, alA, bhA, blA, 0);
  for (int kc = 0; kc < Ks; kc += 64) {
    G3_LOAD(ahB, alB, bhB, blB, kc + 32);
    G3_MFMA(ahA, alA, bhA, blA);
    if (kc + 64 < Ks) G3_LOAD(ahA, alA, bhA, blA, kc + 64);
    G3_MFMA(ahB, alB, bhB, blB);
  }

  // cross-wave reduction: waves 1..3 dump partials, wave 0 sums + epilogue
  if (wv > 0) {
#pragma unroll
    for (int rf = 0; rf < 2; ++rf)
#pragma unroll
      for (int cf = 0; cf < 4; ++cf)
#pragma unroll
        for (int j = 0; j < 4; ++j)
          red[wv - 1][(rf * 4 + cf) * 4 + j][ln] = acc[rf][cf][j];
  }
  __syncthreads();
  if (wv != 0) return;
#pragma unroll
  for (int w = 0; w < 3; ++w)
#pragma unroll
    for (int rf = 0; rf < 2; ++rf)
#pragma unroll
      for (int cf = 0; cf < 4; ++cf)
#pragma unroll
        for (int j = 0; j < 4; ++j)
          acc[rf][cf][j] += red[w][(rf * 4 + cf) * 4 + j][ln];

  if (EPI == 0) {
#pragma unroll
    for (int rf = 0; rf < 2; ++rf)
#pragma unroll
      for (int cf = 0; cf < 4; ++cf) {
        int col = colb + cf * 16 + lrow;
        float bb = bias ? bias[col] : 0.f;
#pragma unroll
        for (int j = 0; j < 4; ++j) {
          int row = rowb + rf * 16 + lk * 4 + j;
          outf[(size_t)row * ldc + col] = acc[rf][cf][j] + bb;
        }
      }
  } else if (EPI == 1) {
    if (colb < D2) {
      float ss[2][4] = {}, sc[2][4] = {};
#pragma unroll
      for (int cf = 0; cf < 4; ++cf) {
        int col = colb + cf * 16 + lrow;
        float bb = bias[col], bc = b2[col];
#pragma unroll
        for (int rf = 0; rf < 2; ++rf)
#pragma unroll
          for (int j = 0; j < 4; ++j) {
            float v = acc[rf][cf][j] + bb;
            ss[rf][j] = fmaf(v, v, ss[rf][j]);
            sc[rf][j] = fmaf(v, bc, sc[rf][j]);
          }
      }
#pragma unroll
      for (int rf = 0; rf < 2; ++rf)
#pragma unroll
        for (int j = 0; j < 4; ++j) {
          float a = ss[rf][j], c = sc[rf][j];
          a += __shfl_xor(a, 1); c += __shfl_xor(c, 1);
          a += __shfl_xor(a, 2); c += __shfl_xor(c, 2);
          a += __shfl_xor(a, 4); c += __shfl_xor(c, 4);
          a += __shfl_xor(a, 8); c += __shfl_xor(c, 8);
          if (lrow == 0) {
            int row = rowb + rf * 16 + lk * 4 + j;
            atomicAdd(&snacc[row], a);
            atomicAdd(&cacc[row], c);
          }
        }
    } else {
#pragma unroll
      for (int rf = 0; rf < 2; ++rf)
#pragma unroll
        for (int cf = 0; cf < 4; ++cf) {
          int col = colb + cf * 16 + lrow;
          float bb = bias[col];
#pragma unroll
          for (int j = 0; j < 4; ++j) {
            int row = rowb + rf * 16 + lk * 4 + j;
            float v = acc[rf][cf][j] + bb;
            if (colb < D2 + G3) gh[(size_t)row * G3 + (col - D2)] = v;
            else                shat[(size_t)row * D2 + (col - (D2 + G3))] = v;
          }
        }
    }
  } else {  // EPI == 2
#pragma unroll
    for (int rf = 0; rf < 2; ++rf)
#pragma unroll
      for (int j = 0; j < 4; ++j) {
        float p = 0.f;
#pragma unroll
        for (int cf = 0; cf < 4; ++cf) {
          int col = colb + cf * 16 + lrow;
          float v = fmaxf(acc[rf][cf][j] + bias[col], 0.f);
          p = fmaf(v, w5w[col], p);
        }
        p += __shfl_xor(p, 1); p += __shfl_xor(p, 2);
        p += __shfl_xor(p, 4); p += __shfl_xor(p, 8);
        if (lrow == 0) atomicAdd(&o3[rowb + rf * 16 + lk * 4 + j], p);
      }
  }
}

// ---------------- dot pass (bf16 m), reads norm accumulators ----------------
__global__ __launch_bounds__(256) void k_dot_bf(const ushort* __restrict__ mbf,
                                                const float* __restrict__ shat3,
                                                const float* __restrict__ norm2,
                                                const float* __restrict__ snacc,
                                                const float* __restrict__ cacc,
                                                const int* __restrict__ mask,
                                                float* __restrict__ att3) {
  __shared__ float sh[3][512];
  int b = blockIdx.x >> 3;
  int lt = blockIdx.x & 7;
  int tid = threadIdx.x;
  for (int k = 0; k < 3; ++k)
    for (int i = tid; i < 512; i += 256) sh[k][i] = shat3[(size_t)(k * B + b) * D2 + i];
  __syncthreads();
  int j = tid & 3, lidx = tid >> 2;
  int l = lt * 64 + lidx;
  const uint4* mrow = reinterpret_cast<const uint4*>(mbf + (size_t)(b * L + l) * D2);
  float a0 = 0.f, a1 = 0.f, a2 = 0.f;
#pragma unroll 4
  for (int s = 0; s < 16; ++s) {
    int c = s * 4 + j;
    uint4 mv = mrow[c];
    const float* p0 = &sh[0][c * 8];
    const float* p1 = &sh[1][c * 8];
    const float* p2 = &sh[2][c * 8];
    uint w[4] = {mv.x, mv.y, mv.z, mv.w};
#pragma unroll
    for (int q = 0; q < 4; ++q) {
      float lo = bflo(w[q]), hi = bfhi(w[q]);
      a0 = fmaf(lo, p0[q * 2], a0); a0 = fmaf(hi, p0[q * 2 + 1], a0);
      a1 = fmaf(lo, p1[q * 2], a1); a1 = fmaf(hi, p1[q * 2 + 1], a1);
      a2 = fmaf(lo, p2[q * 2], a2); a2 = fmaf(hi, p2[q * 2 + 1], a2);
    }
  }
  a0 += __shfl_xor(a0, 1); a0 += __shfl_xor(a0, 2);
  a1 += __shfl_xor(a1, 1); a1 += __shfl_xor(a1, 2);
  a2 += __shfl_xor(a2, 1); a2 += __shfl_xor(a2, 2);
  if (j == 0) {
    float mn = fmaxf(sqrtf(norm2[b * L + l]), EPSF);
    bool inv = (mask[b * L + l] == 0);
    float ar[3] = {a0, a1, a2};
#pragma unroll
    for (int k = 0; k < 3; ++k) {
      int r = k * B + b;
      float sn = fmaxf(sqrtf(snacc[r]), EPSF);
      float att = LAMDA * (ar[k] + cacc[r]) / (mn * sn);
      att3[(size_t)r * L + l] = inv ? -INFINITY : att;
    }
  }
}

// ---------------- fused softmax + f_att (raw att in, split planes out) ----------------
__global__ __launch_bounds__(256) void k_fatt_sm(const ushort* __restrict__ mbf,
                                                 const float* __restrict__ att3,
                                                 ushort* __restrict__ fatth,
                                                 ushort* __restrict__ fattl) {
  __shared__ float pp[3][512];
  __shared__ float red[3][256];
  __shared__ float inv3[3];
  int b = blockIdx.x >> 1, dt = blockIdx.x & 1;
  int tid = threadIdx.x;
  for (int k = 0; k < 3; ++k)
    for (int i = tid; i < 512; i += 256) pp[k][i] = att3[(size_t)(k * B + b) * L + i];
  __syncthreads();
  int wv = tid >> 6, ln = tid & 63;
  if (wv < 3) {
    float x[8];
#pragma unroll
    for (int i = 0; i < 8; ++i) x[i] = pp[wv][ln + 64 * i];
    float mx = x[0];
#pragma unroll
    for (int i = 1; i < 8; ++i) mx = fmaxf(mx, x[i]);
    for (int o = 32; o; o >>= 1) mx = fmaxf(mx, __shfl_xor(mx, o));
    float e[8], s = 0.f;
#pragma unroll
    for (int i = 0; i < 8; ++i) { e[i] = expf(x[i] - mx); s += e[i]; }
    for (int o = 32; o; o >>= 1) s += __shfl_xor(s, o);
#pragma unroll
    for (int i = 0; i < 8; ++i) pp[wv][ln + 64 * i] = e[i];
    if (ln == 0) inv3[wv] = 1.0f / s;
  }
  __syncthreads();
  int dpair = tid & 127, half = tid >> 7;
  int d = dt * 256 + dpair * 2;
  float a[3][2] = {};
  int l0 = half * 256;
#pragma unroll 4
  for (int l = l0; l < l0 + 256; ++l) {
    uint w = *reinterpret_cast<const uint*>(&mbf[(size_t)(b * L + l) * D2 + d]);
    float f0 = bflo(w), f1 = bfhi(w);
#pragma unroll
    for (int k = 0; k < 3; ++k) {
      float p = pp[k][l];
      a[k][0] = fmaf(p, f0, a[k][0]);
      a[k][1] = fmaf(p, f1, a[k][1]);
    }
  }
  if (half == 1) {
#pragma unroll
    for (int k = 0; k < 3; ++k) { red[k][dpair * 2] = a[k][0]; red[k][dpair * 2 + 1] = a[k][1]; }
  }
  __syncthreads();
  if (half == 0) {
#pragma unroll
    for (int k = 0; k < 3; ++k) {
      float sc = inv3[k];
      float v0 = (a[k][0] + red[k][dpair * 2]) * sc;
      float v1 = (a[k][1] + red[k][dpair * 2 + 1]) * sc;
      ushort h0, l0u, h1, l1u;
      split2(v0, h0, l0u); split2(v1, h1, l1u);
      size_t o = (size_t)(k * B + b) * D2 + d;
      fatth[o] = h0;     fattl[o] = l0u;
      fatth[o + 1] = h1; fattl[o + 1] = l1u;
    }
  }
}

// ---------------- GRU gates (+ zero norm accumulators for next hop) ----------------
__global__ void k_gates(const float* __restrict__ gx, const float* __restrict__ gh,
                        float* __restrict__ st3,
                        ushort* __restrict__ sth, ushort* __restrict__ stl,
                        float* __restrict__ snacc, float* __restrict__ cacc) {
  int idx = blockIdx.x * blockDim.x + threadIdx.x;
  if (snacc && idx < R3) { snacc[idx] = 0.f; cacc[idx] = 0.f; }
  if (idx >= R3 * D4) return;
  int r = idx / D4, i = idx - r * D4;
  const float* gxr = gx + (size_t)r * G3;
  const float* ghr = gh + (size_t)r * G3;
  float xr = gxr[i], xz = gxr[D4 + i], xn = gxr[2 * D4 + i];
  float hr = ghr[i], hz = ghr[D4 + i], hn = ghr[2 * D4 + i];
  float rr = 1.f / (1.f + expf(-(xr + hr)));
  float zz = 1.f / (1.f + expf(-(xz + hz)));
  float nn = tanhf(xn + rr * hn);
  float h = st3[idx];
  float nv = (1.f - zz) * nn + zz * h;
  st3[idx] = nv;
  if (sth) { ushort hh, ll; split2(nv, hh, ll); sth[idx] = hh; stl[idx] = ll; }
}

// ---------------- final log_softmax ----------------
__global__ void k_final(const float* __restrict__ o3, const float* __restrict__ w5b,
                        float* __restrict__ out) {
  int b = threadIdx.x;
  if (b >= B) return;
  float v0 = o3[0 * B + b] + w5b[0];
  float v1 = o3[1 * B + b] + w5b[0];
  float v2 = o3[2 * B + b] + w5b[0];
  float mx = fmaxf(v0, fmaxf(v1, v2));
  float s = expf(v0 - mx) + expf(v1 - mx) + expf(v2 - mx);
  float lse = mx + logf(s);
  out[b * 3 + 0] = v0 - lse;
  out[b * 3 + 1] = v1 - lse;
  out[b * 3 + 2] = v2 - lse;
}

// ================= fallback f32 kernels (small-ws path) =================
__global__ __launch_bounds__(256) void k_mnorm(const float* __restrict__ m,
                                               const float* __restrict__ w2,
                                               const float* __restrict__ b2,
                                               float* __restrict__ norm2) {
  __shared__ float As[64][33];
  __shared__ float Ws[32][65];
  __shared__ float red[16][64];
  const int tid = threadIdx.x;
  const int ty = tid >> 4, tx = tid & 15;
  const long rowb = (long)blockIdx.x * 64;
  float rowpart[4] = {0.f, 0.f, 0.f, 0.f};
  for (int ct = 0; ct < 8; ++ct) {
    float acc[4][4] = {};
    for (int kc = 0; kc < 16; ++kc) {
#pragma unroll
      for (int i = 0; i < 8; ++i) {
        int li = tid + i * 256;
        int r = li >> 5, c = li & 31;
        As[r][c] = m[(rowb + r) * 512 + kc * 32 + c];
      }
#pragma unroll
      for (int i = 0; i < 8; ++i) {
        int li = tid + i * 256;
        int r = li >> 6, c = li & 63;
        Ws[r][c] = w2[(kc * 32 + r) * 512 + ct * 64 + c];
      }
      __syncthreads();
#pragma unroll
      for (int k = 0; k < 32; ++k) {
        float a[4], bb[4];
#pragma unroll
        for (int i = 0; i < 4; ++i) a[i] = As[ty * 4 + i][k];
#pragma unroll
        for (int jj = 0; jj < 4; ++jj) bb[jj] = Ws[k][tx * 4 + jj];
#pragma unroll
        for (int i = 0; i < 4; ++i)
#pragma unroll
          for (int jj = 0; jj < 4; ++jj) acc[i][jj] = fmaf(a[i], bb[jj], acc[i][jj]);
      }
      __syncthreads();
    }
#pragma unroll
    for (int jj = 0; jj < 4; ++jj) {
      float bj = b2[ct * 64 + tx * 4 + jj];
#pragma unroll
      for (int i = 0; i < 4; ++i) {
        float v = acc[i][jj] + bj;
        rowpart[i] = fmaf(v, v, rowpart[i]);
      }
    }
  }
#pragma unroll
  for (int i = 0; i < 4; ++i) red[tx][ty * 4 + i] = rowpart[i];
  __syncthreads();
  if (tid < 64) {
    float s = 0.f;
#pragma unroll
    for (int t = 0; t < 16; ++t) s += red[t][tid];
    norm2[rowb + tid] = s;
  }
}

template <bool BT, int ACT>
__global__ __launch_bounds__(256) void k_gemm64(const float* __restrict__ A, int lda,
                                                const float* __restrict__ Bm, int ldb,
                                                const float* __restrict__ bias,
                                                float* __restrict__ C, int ldc, int Kd) {
  __shared__ float As[64][33];
  __shared__ float Bs[32][65];
  const int tid = threadIdx.x;
  const int ty = tid >> 4, tx = tid & 15;
  const int rowb = blockIdx.y * 64;
  const int colb = blockIdx.x * 64;
  float acc[4][4] = {};
  for (int kc = 0; kc < Kd; kc += 32) {
#pragma unroll
    for (int i = 0; i < 8; ++i) {
      int li = tid + i * 256;
      int r = li >> 5, c = li & 31;
      As[r][c] = A[(long)(rowb + r) * lda + kc + c];
    }
    if (!BT) {
#pragma unroll
      for (int i = 0; i < 8; ++i) {
        int li = tid + i * 256;
        int r = li >> 6, c = li & 63;
        Bs[r][c] = Bm[(long)(kc + r) * ldb + colb + c];
      }
    } else {
#pragma unroll
      for (int i = 0; i < 8; ++i) {
        int li = tid + i * 256;
        int n = li >> 5, k = li & 31;
        Bs[k][n] = Bm[(long)(colb + n) * ldb + kc + k];
      }
    }
    __syncthreads();
#pragma unroll
    for (int k = 0; k < 32; ++k) {
      float a[4], bb[4];
#pragma unroll
      for (int i = 0; i < 4; ++i) a[i] = As[ty * 4 + i][k];
#pragma unroll
      for (int jj = 0; jj < 4; ++jj) bb[jj] = Bs[k][tx * 4 + jj];
#pragma unroll
      for (int i = 0; i < 4; ++i)
#pragma unroll
        for (int jj = 0; jj < 4; ++jj) acc[i][jj] = fmaf(a[i], bb[jj], acc[i][jj]);
    }
    __syncthreads();
  }
#pragma unroll
  for (int i = 0; i < 4; ++i) {
    int row = rowb + ty * 4 + i;
#pragma unroll
    for (int jj = 0; jj < 4; ++jj) {
      int col = colb + tx * 4 + jj;
      float v = acc[i][jj];
      if (bias) v += bias[col];
      if (ACT == 1) v = fmaxf(v, 0.f);
      C[(long)row * ldc + col] = v;
    }
  }
}

__global__ void k_snorm(const float* __restrict__ stt3, const float* __restrict__ b2,
                        float* __restrict__ sn3, float* __restrict__ c3) {
  int r = blockIdx.x;
  int tid = threadIdx.x;
  float ss = 0.f, sc = 0.f;
  for (int j = tid; j < D2; j += 256) {
    float v = stt3[(size_t)r * D2 + j];
    ss = fmaf(v, v, ss);
    sc = fmaf(v, b2[j], sc);
  }
  for (int o = 32; o; o >>= 1) {
    ss += __shfl_down(ss, o);
    sc += __shfl_down(sc, o);
  }
  __shared__ float rs[4], rc[4];
  int w = tid >> 6;
  if ((tid & 63) == 0) { rs[w] = ss; rc[w] = sc; }
  __syncthreads();
  if (tid == 0) {
    sn3[r] = fmaxf(sqrtf(rs[0] + rs[1] + rs[2] + rs[3]), EPSF);
    c3[r] = rc[0] + rc[1] + rc[2] + rc[3];
  }
}

__global__ __launch_bounds__(256) void k_dot(const float* __restrict__ m,
                                             const float* __restrict__ shat3,
                                             const float* __restrict__ norm2,
                                             const float* __restrict__ sn3,
                                             const float* __restrict__ c3,
                                             const int* __restrict__ mask,
                                             float* __restrict__ att3) {
  __shared__ float sh[3][512];
  int b = blockIdx.x >> 3;
  int lt = blockIdx.x & 7;
  int tid = threadIdx.x;
  for (int k = 0; k < 3; ++k)
    for (int i = tid; i < 512; i += 256) sh[k][i] = shat3[(size_t)(k * B + b) * D2 + i];
  __syncthreads();
  int j = tid & 3, lidx = tid >> 2;
  int l = lt * 64 + lidx;
  const float4* mrow = reinterpret_cast<const float4*>(m + (size_t)(b * L + l) * D2);
  float a0 = 0.f, a1 = 0.f, a2 = 0.f;
#pragma unroll 8
  for (int s = 0; s < 32; ++s) {
    int d4 = s * 4 + j;
    float4 mv = mrow[d4];
    const float4 v0 = *reinterpret_cast<const float4*>(&sh[0][d4 * 4]);
    const float4 v1 = *reinterpret_cast<const float4*>(&sh[1][d4 * 4]);
    const float4 v2 = *reinterpret_cast<const float4*>(&sh[2][d4 * 4]);
    a0 += mv.x * v0.x + mv.y * v0.y + mv.z * v0.z + mv.w * v0.w;
    a1 += mv.x * v1.x + mv.y * v1.y + mv.z * v1.z + mv.w * v1.w;
    a2 += mv.x * v2.x + mv.y * v2.y + mv.z * v2.z + mv.w * v2.w;
  }
  a0 += __shfl_xor(a0, 1); a0 += __shfl_xor(a0, 2);
  a1 += __shfl_xor(a1, 1); a1 += __shfl_xor(a1, 2);
  a2 += __shfl_xor(a2, 1); a2 += __shfl_xor(a2, 2);
  if (j == 0) {
    float mn = fmaxf(sqrtf(norm2[b * L + l]), EPSF);
    bool inv = (mask[b * L + l] == 0);
    float ar[3] = {a0, a1, a2};
#pragma unroll
    for (int k = 0; k < 3; ++k) {
      int r = k * B + b;
      float att = LAMDA * (ar[k] + c3[r]) / (mn * sn3[r]);
      att3[(size_t)r * L + l] = inv ? -INFINITY : att;
    }
  }
}

__global__ void k_softmax(float* __restrict__ att3) {
  int r = blockIdx.x;
  float* row = att3 + (size_t)r * L;
  int tid = threadIdx.x;
  float x0 = row[tid], x1 = row[tid + 256];
  float mx = fmaxf(x0, x1);
  for (int o = 32; o; o >>= 1) mx = fmaxf(mx, __shfl_xor(mx, o));
  __shared__ float rm[4], rs[4];
  int w = tid >> 6;
  if ((tid & 63) == 0) rm[w] = mx;
  __syncthreads();
  mx = fmaxf(fmaxf(rm[0], rm[1]), fmaxf(rm[2], rm[3]));
  float e0 = expf(x0 - mx), e1 = expf(x1 - mx);
  float s = e0 + e1;
  for (int o = 32; o; o >>= 1) s += __shfl_xor(s, o);
  if ((tid & 63) == 0) rs[w] = s;
  __syncthreads();
  s = rs[0] + rs[1] + rs[2] + rs[3];
  float inv = 1.0f / s;
  row[tid] = e0 * inv;
  row[tid + 256] = e1 * inv;
}

__global__ __launch_bounds__(256) void k_fatt(const float* __restrict__ m,
                                              const float* __restrict__ p3,
                                              float* __restrict__ fatt3) {
  __shared__ float pp[3][512];
  __shared__ float red[3][128];
  int b = blockIdx.x >> 2, dt = blockIdx.x & 3;
  int tid = threadIdx.x;
  for (int k = 0; k < 3; ++k)
    for (int i = tid; i < 512; i += 256) pp[k][i] = p3[(size_t)(k * B + b) * L + i];
  __syncthreads();
  int d = dt * 128 + (tid & 127);
  int half = tid >> 7;
  float a0 = 0.f, a1 = 0.f, a2 = 0.f;
  int l0 = half * 256;
  for (int l = l0; l < l0 + 256; ++l) {
    float mv = m[(size_t)(b * L + l) * D2 + d];
    a0 = fmaf(pp[0][l], mv, a0);
    a1 = fmaf(pp[1][l], mv, a1);
    a2 = fmaf(pp[2][l], mv, a2);
  }
  int dd = tid & 127;
  if (half == 1) { red[0][dd] = a0; red[1][dd] = a1; red[2][dd] = a2; }
  __syncthreads();
  if (half == 0) {
    fatt3[(size_t)(0 * B + b) * D2 + d] = a0 + red[0][dd];
    fatt3[(size_t)(1 * B + b) * D2 + d] = a1 + red[1][dd];
    fatt3[(size_t)(2 * B + b) * D2 + d] = a2 + red[2][dd];
  }
}

__global__ void k_w5(const float* __restrict__ h4, const float* __restrict__ w5w,
                     float* __restrict__ o3) {
  int r = blockIdx.x, tid = threadIdx.x;
  float s = 0.f;
  for (int d = tid; d < D4; d += 256) s = fmaf(h4[(size_t)r * D4 + d], w5w[d], s);
  for (int o = 32; o; o >>= 1) s += __shfl_down(s, o);
  __shared__ float rs[4];
  if ((tid & 63) == 0) rs[tid >> 6] = s;
  __syncthreads();
  if (tid == 0) o3[r] = rs[0] + rs[1] + rs[2] + rs[3];
}

extern "C" void kernel_launch(void* const* d_in, const int* in_sizes, int n_in,
                              void* d_out, int out_size, void* d_ws, size_t ws_size,
                              hipStream_t stream) {
  const float* m    = (const float*)d_in[0];
  const float* s1   = (const float*)d_in[1];
  const float* s2   = (const float*)d_in[2];
  const float* s3   = (const float*)d_in[3];
  const int*   mask = (const int*)d_in[4];
  const float* w2w  = (const float*)d_in[5];
  const float* w2b  = (const float*)d_in[6];
  const float* w3w  = (const float*)d_in[7];
  const float* w3b  = (const float*)d_in[8];
  const float* w4w  = (const float*)d_in[9];
  const float* w4b  = (const float*)d_in[10];
  const float* w5w  = (const float*)d_in[11];
  const float* w5b  = (const float*)d_in[12];
  const float* gwi  = (const float*)d_in[13];
  const float* gwh  = (const float*)d_in[14];
  const float* gbi  = (const float*)d_in[15];
  const float* gbh  = (const float*)d_in[16];
  float* out = (float*)d_out;

  float* ws = (float*)d_ws;
  size_t off = 0;
  auto alloc = [&](size_t n) {
    float* p = ws + off;
    off += (n + 63) & ~(size_t)63;
    return p;
  };
  ushort* mbf   = (ushort*)alloc((size_t)B * L * D2 / 2);
  ushort* w2t   = (ushort*)alloc((size_t)D2 * D2 / 2);
  ushort* catBh = (ushort*)alloc((size_t)NC * D4 / 2);
  ushort* catBl = (ushort*)alloc((size_t)NC * D4 / 2);
  ushort* gxBh  = (ushort*)alloc((size_t)G3 * D2 / 2);
  ushort* gxBl  = (ushort*)alloc((size_t)G3 * D2 / 2);
  ushort* w4Bh  = (ushort*)alloc((size_t)D4 * D4 / 2);
  ushort* w4Bl  = (ushort*)alloc((size_t)D4 * D4 / 2);
  float* bcat   = alloc(NC);
  float* norm2  = alloc((size_t)B * L);
  float* st3    = alloc((size_t)R3 * D4);
  ushort* sth   = (ushort*)alloc((size_t)R3 * D4 / 2);
  ushort* stl   = (ushort*)alloc((size_t)R3 * D4 / 2);
  float* shat3  = alloc((size_t)R3 * D2);
  float* snacc  = alloc(R3);
  float* cacc   = alloc(R3);
  float* o3     = alloc(R3);
  ushort* fatth = (ushort*)alloc((size_t)R3 * D2 / 2);
  ushort* fattl = (ushort*)alloc((size_t)R3 * D2 / 2);
  float* att3   = alloc((size_t)R3 * L);
  float* gx     = alloc((size_t)R3 * G3);
  float* gh     = alloc((size_t)R3 * G3);
  const size_t big_need = off;
  const bool big = ws_size >= big_need * sizeof(float);

  if (big) {
    ushort* w2dh = (ushort*)gh;
    ushort* w2dl = w2dh + (size_t)D2 * D2;
    ushort* w3dh = (ushort*)gx;
    ushort* w3dl = w3dh + (size_t)D4 * D2;

    k_init<<<1536, 256, 0, stream>>>(s1, s2, s3, st3, sth, stl, snacc, cacc, o3);
    k_conv_m<<<2048, 256, 0, stream>>>(m, mbf);
    k_w2t<<<64, 256, 0, stream>>>(w2w, w2t);
    k_mnorm4<<<(B * L) / 64, 256, 0, stream>>>(mbf, w2t, w2b, norm2);
    k_split_trans<<<dim3(D4 / 64, D2 / 64), 256, 0, stream>>>(w3w, D4, D2, catBh, catBl);
    // fused direct splits: gwh -> catB tail | gwi -> gxB | w2 -> w2d | w3 -> w3d
    k_split4<<<2048, 256, 0, stream>>>(
        gwh, catBh + (size_t)D2 * D4, catBl + (size_t)D2 * D4, (G3 * D4) / 4,
        gwi, gxBh, gxBl, (G3 * D2) / 4,
        w2w, w2dh, w2dl, (D2 * D2) / 4,
        w3w, w3dh, w3dl, (D4 * D2) / 4);
    k_split_trans<<<dim3(D4 / 64, D4 / 64), 256, 0, stream>>>(w4w, D4, D4, w4Bh, w4Bl);
    k_bcat2<<<16, 256, 0, stream>>>(w3b, gbh, w2w, bcat);
    k_gemm_wf<<<dim3(D4 / 64, D2 / 64), 64, 0, stream>>>(
        w2dh, w2dl, w3dh, w3dl,
        catBh + (size_t)(D2 + G3) * D4, catBl + (size_t)(D2 + G3) * D4);

    for (int hop = 0; hop < 3; ++hop) {
      k_gemm5<1><<<dim3(NC / 64, R3 / 32), 256, 0, stream>>>(
          sth, stl, catBh, catBl, D4, bcat, nullptr, 0,
          gh, shat3, snacc, cacc, w2b, nullptr, nullptr);
      k_dot_bf<<<B * 8, 256, 0, stream>>>(mbf, shat3, norm2, snacc, cacc, mask, att3);
      k_fatt_sm<<<B * 2, 256, 0, stream>>>(mbf, att3, fatth, fattl);
      k_gemm5<0><<<dim3(G3 / 64, R3 / 32), 256, 0, stream>>>(
          fatth, fattl, gxBh, gxBl, D2, gbi, gx, G3,
          nullptr, nullptr, nullptr, nullptr, nullptr, nullptr, nullptr);
      k_gates<<<1536, 256, 0, stream>>>(gx, gh, st3, sth, stl, snacc, cacc);
    }
    k_gemm5<2><<<dim3(D4 / 64, R3 / 32), 256, 0, stream>>>(
        sth, stl, w4Bh, w4Bl, D4, w4b, nullptr, 0,
        nullptr, nullptr, nullptr, nullptr, nullptr, w5w, o3);
    k_final<<<1, 128, 0, stream>>>(o3, w5b, out);
  } else {
    off = 0;
    float* f_st3   = alloc((size_t)R3 * D4);
    float* f_norm2 = alloc((size_t)B * L);
    float* f_stt   = alloc((size_t)R3 * D2);
    float* f_shat  = alloc((size_t)R3 * D2);
    float* f_sn    = alloc(R3);
    float* f_c     = alloc(R3);
    float* f_att   = alloc((size_t)R3 * L);
    float* f_fatt  = alloc((size_t)R3 * D2);
    float* f_gx    = alloc((size_t)R3 * G3);
    float* f_gh    = alloc((size_t)R3 * G3);
    float* f_h4    = alloc((size_t)R3 * D4);
    float* f_o3    = alloc(R3);
    k_init<<<1536, 256, 0, stream>>>(s1, s2, s3, f_st3, nullptr, nullptr, f_sn, f_c, f_o3);
    k_mnorm<<<(B * L) / 64, 256, 0, stream>>>(m, w2w, w2b, f_norm2);
    for (int hop = 0; hop < 3; ++hop) {
      k_gemm64<false, 0><<<dim3(D2 / 64, R3 / 64), 256, 0, stream>>>(f_st3, D4, w3w, D2, w3b, f_stt, D2, D4);
      k_snorm<<<R3, 256, 0, stream>>>(f_stt, w2b, f_sn, f_c);
      k_gemm64<true, 0><<<dim3(D2 / 64, R3 / 64), 256, 0, stream>>>(f_stt, D2, w2w, D2, nullptr, f_shat, D2, D2);
      k_dot<<<B * 8, 256, 0, stream>>>(m, f_shat, f_norm2, f_sn, f_c, mask, f_att);
      k_softmax<<<3 * B, 256, 0, stream>>>(f_att);
      k_fatt<<<B * 4, 256, 0, stream>>>(m, f_att, f_fatt);
      k_gemm64<true, 0><<<dim3(G3 / 64, R3 / 64), 256, 0, stream>>>(f_fatt, D2, gwi, D2, gbi, f_gx, G3, D2);
      k_gemm64<true, 0><<<dim3(G3 / 64, R3 / 64), 256, 0, stream>>>(f_st3, D4, gwh, D4, gbh, f_gh, G3, D4);
      k_gates<<<1536, 256, 0, stream>>>(f_gx, f_gh, f_st3, nullptr, nullptr, nullptr, nullptr);
    }
    k_gemm64<false, 1><<<dim3(D4 / 64, R3 / 64), 256, 0, stream>>>(f_st3, D4, w4w, D4, w4b, f_h4, D4, D4);
    k_w5<<<R3, 256, 0, stream>>>(f_h4, w5w, f_o3);
    k_final<<<1, 128, 0, stream>>>(f_o3, w5b, out);
  }
}